// Round 7
// baseline (339.162 us; speedup 1.0000x reference)
//
#include <hip/hip_runtime.h>
#include <math.h>

#define N_NODES 100000
#define N_EDGES 1600000
#define IN_C    128
#define HID     256
#define KEIG    64
#define OUT_C   16

#define NPB      256                                   // nodes per bucket
#define NBUCKET  ((N_NODES + NPB - 1) / NPB)           // 391
#define EDGE_TILE 4096
#define NTILE    ((N_EDGES + EDGE_TILE - 1) / EDGE_TILE) // 391

#define TRANS_BLOCKS   ((N_NODES + 63) / 64)
#define GATHER_BLOCKS  2048
#define CUT_BLOCKS     2048
#define SSP_BLOCKS     512
#define OUT_BLOCKS     ((N_NODES + 255) / 256)

typedef __attribute__((ext_vector_type(8))) short short8;
typedef __attribute__((ext_vector_type(4))) float f32x4;

__device__ __forceinline__ float wave_sum(float v) {
#pragma unroll
    for (int m = 32; m; m >>= 1) v += __shfl_xor(v, m, 64);
    return v;
}
__device__ __forceinline__ float wave_max(float v) {
#pragma unroll
    for (int m = 32; m; m >>= 1) v = fmaxf(v, __shfl_xor(v, m, 64));
    return v;
}
__device__ __forceinline__ float bf2f(unsigned int u) {
    return __uint_as_float((u & 0xffffu) << 16);
}
__device__ __forceinline__ unsigned short f2bf(float f) {
    unsigned int u = __float_as_uint(f);
    u += 0x7fff + ((u >> 16) & 1);
    return (unsigned short)(u >> 16);
}
__device__ __forceinline__ float fp8tof(int b) {
    return __builtin_amdgcn_cvt_f32_fp8(b, 0);
}
__device__ __forceinline__ unsigned char f2fp8(float f) {
    int p = __builtin_amdgcn_cvt_pk_fp8_f32(f, f, 0, false);
    return (unsigned char)(p & 0xff);
}

#define FMA4(P, s, W) \
    P.x = fmaf(s, W.x, P.x); P.y = fmaf(s, W.y, P.y); \
    P.z = fmaf(s, W.z, P.z); P.w = fmaf(s, W.w, P.w);

// ---------------- small precompute (+ zero bucket counts) ----------------
__global__ void prep_weff(const float* __restrict__ mlpxW, const float* __restrict__ mlpxb,
                          const float* __restrict__ finW, const float* __restrict__ finb,
                          float* __restrict__ Weff, float* __restrict__ beff,
                          int* __restrict__ bcnt) {
    int t = blockIdx.x * blockDim.x + threadIdx.x;
    const int NW = (IN_C + KEIG) * OUT_C;
    if (t < NW) {
        int k = t >> 4, o = t & 15;
        float acc;
        if (k < IN_C) {
            acc = 0.f;
            for (int c = 0; c < HID; ++c)
                acc += mlpxW[c * IN_C + k] * finW[o * (HID + KEIG) + c];
        } else {
            acc = finW[o * (HID + KEIG) + HID + (k - IN_C)];
        }
        Weff[k * OUT_C + o] = acc;
    }
    int tb = t - NW;
    if (tb >= 0 && tb < OUT_C) {
        float acc = finb[tb];
        for (int c = 0; c < HID; ++c) acc += mlpxb[c] * finW[tb * (HID + KEIG) + c];
        beff[tb] = acc;
    }
    int tz = t - (NW + OUT_C);
    if (tz >= 0 && tz <= NBUCKET) bcnt[tz] = 0;
}

// MLP_W [64, N] -> WT8 [N, 64] fp8 (scaled x32)
__global__ void transpose_w(const float* __restrict__ W, unsigned char* __restrict__ WT8) {
    __shared__ float tile[64][65];
    int n0 = blockIdx.x * 64;
    int t = threadIdx.x;
    int tn = t & 63, tq = t >> 6;
#pragma unroll
    for (int kk = 0; kk < 16; ++kk) {
        int k = tq * 16 + kk;
        int n = n0 + tn;
        tile[k][tn] = (n < N_NODES) ? W[(long long)k * N_NODES + n] : 0.f;
    }
    __syncthreads();
    int tk = t & 63;
#pragma unroll
    for (int ii = 0; ii < 16; ++ii) {
        int n = n0 + tq * 16 + ii;
        if (n < N_NODES) WT8[(unsigned)n * 64u + tk] = f2fp8(tile[tk][tq * 16 + ii] * 32.f);
    }
}

// ---------------- bucket sort CSR build ----------------
__global__ void bucket_hist(const int* __restrict__ ei, int* __restrict__ bcnt) {
    __shared__ int h[NBUCKET];
    int t = threadIdx.x;
    for (int i = t; i < NBUCKET; i += 256) h[i] = 0;
    __syncthreads();
    int e0 = blockIdx.x * EDGE_TILE;
    int e1 = min(e0 + EDGE_TILE, N_EDGES);
    for (int e = e0 + t; e < e1; e += 256)
        atomicAdd(&h[ei[N_EDGES + e] >> 8], 1);
    __syncthreads();
    for (int i = t; i < NBUCKET; i += 256)
        if (h[i]) atomicAdd(&bcnt[i], h[i]);
}

__global__ void bucket_scan(const int* __restrict__ bcnt, int* __restrict__ bbase,
                            int* __restrict__ bcur) {
    __shared__ int sh[512];
    int t = threadIdx.x;
    int v = (t < NBUCKET) ? bcnt[t] : 0;
    sh[t] = v;
    __syncthreads();
    for (int d = 1; d < 512; d <<= 1) {
        int u = (t >= d) ? sh[t - d] : 0;
        __syncthreads();
        sh[t] += u;
        __syncthreads();
    }
    if (t < NBUCKET) { bbase[t] = sh[t] - v; bcur[t] = sh[t] - v; }
    if (t == 0) bbase[NBUCKET] = N_EDGES;
}

// partition edges into bucket regions; pack r | (local_col << 17)
__global__ void bucket_scatter(const int* __restrict__ ei, int* __restrict__ bcur,
                               int* __restrict__ ebuf) {
    __shared__ int h[NBUCKET];
    __shared__ int gb[NBUCKET];
    int t = threadIdx.x;
    for (int i = t; i < NBUCKET; i += 256) h[i] = 0;
    __syncthreads();
    int e0 = blockIdx.x * EDGE_TILE;
    int e1 = min(e0 + EDGE_TILE, N_EDGES);
    for (int e = e0 + t; e < e1; e += 256)
        atomicAdd(&h[ei[N_EDGES + e] >> 8], 1);
    __syncthreads();
    for (int i = t; i < NBUCKET; i += 256) {
        int c = h[i];
        gb[i] = c ? atomicAdd(&bcur[i], c) : 0;
        h[i] = 0;                                // reuse as local cursor
    }
    __syncthreads();
    for (int e = e0 + t; e < e1; e += 256) {
        int r = ei[e];
        int c = ei[N_EDGES + e];
        int b = c >> 8;
        int pos = gb[b] + atomicAdd(&h[b], 1);
        ebuf[pos] = r | ((c & 255) << 17);
    }
}

// one block per bucket: LDS hist + scan -> offsets; LDS cursors -> csr_row
__global__ void csr_build(const int* __restrict__ ebuf, const int* __restrict__ bbase,
                          int* __restrict__ offsets, int* __restrict__ csr_row) {
    __shared__ int hist[NPB];
    __shared__ int sh[NPB];
    __shared__ int curs[NPB];
    int b = blockIdx.x;
    int t = threadIdx.x;
    int s0 = bbase[b], s1 = bbase[b + 1];
    hist[t] = 0;
    __syncthreads();
    for (int i = s0 + t; i < s1; i += 256)
        atomicAdd(&hist[ebuf[i] >> 17], 1);
    __syncthreads();
    int v = hist[t];
    sh[t] = v;
    __syncthreads();
    for (int d = 1; d < 256; d <<= 1) {
        int u = (t >= d) ? sh[t - d] : 0;
        __syncthreads();
        sh[t] += u;
        __syncthreads();
    }
    int excl = s0 + sh[t] - v;
    int node = b * NPB + t;
    if (node < N_NODES) offsets[node] = excl;
    curs[t] = excl;
    __syncthreads();
    for (int i = s0 + t; i < s1; i += 256) {
        int pk = ebuf[i];
        int pos = atomicAdd(&curs[pk >> 17], 1);
        csr_row[pos] = pk & 0x1FFFF;
    }
    if (b == 0 && t == 0) offsets[N_NODES] = N_EDGES;
}

// ---------------- pass 1: fp8 gather + bias + softmax + deg_term ----------------
__global__ void gather_softmax(const int* __restrict__ offsets, const int* __restrict__ csr_row,
                               const unsigned char* __restrict__ WT8,
                               const float* __restrict__ MLPb,
                               unsigned short* __restrict__ Sb,
                               unsigned char* __restrict__ S8,
                               float* __restrict__ dtp) {
    int lane = threadIdx.x & 63;
    int wib = threadIdx.x >> 6;
    int gw = (blockIdx.x * blockDim.x + threadIdx.x) >> 6;
    int nw = (gridDim.x * blockDim.x) >> 6;
    float bias = MLPb[lane];
    float dacc = 0.f;
    for (int n = gw; n < N_NODES; n += nw) {
        int s0 = offsets[n], s1 = offsets[n + 1];
        float acc = 0.f;
        for (int base = s0; base < s1; base += 64) {
            int cnt = min(64, s1 - base);
            int rv = (lane < cnt) ? csr_row[base + lane] : 0;
            int j = 0;
            for (; j + 7 < cnt; j += 8) {
                unsigned o0 = (unsigned)__shfl(rv, j, 64) * 64u + lane;
                unsigned o1 = (unsigned)__shfl(rv, j + 1, 64) * 64u + lane;
                unsigned o2 = (unsigned)__shfl(rv, j + 2, 64) * 64u + lane;
                unsigned o3 = (unsigned)__shfl(rv, j + 3, 64) * 64u + lane;
                unsigned o4 = (unsigned)__shfl(rv, j + 4, 64) * 64u + lane;
                unsigned o5 = (unsigned)__shfl(rv, j + 5, 64) * 64u + lane;
                unsigned o6 = (unsigned)__shfl(rv, j + 6, 64) * 64u + lane;
                unsigned o7 = (unsigned)__shfl(rv, j + 7, 64) * 64u + lane;
                int b0 = WT8[o0], b1 = WT8[o1], b2 = WT8[o2], b3 = WT8[o3];
                int b4 = WT8[o4], b5 = WT8[o5], b6 = WT8[o6], b7 = WT8[o7];
                acc += ((fp8tof(b0) + fp8tof(b1)) + (fp8tof(b2) + fp8tof(b3)))
                     + ((fp8tof(b4) + fp8tof(b5)) + (fp8tof(b6) + fp8tof(b7)));
            }
            for (; j < cnt; ++j) {
                unsigned o = (unsigned)__shfl(rv, j, 64) * 64u + lane;
                acc += fp8tof(WT8[o]);
            }
        }
        acc = bias + acc * 0.03125f;   // undo x32 scale
        float m = wave_max(acc);
        float e = __expf(acc - m);
        float sm = wave_sum(e);
        float sv = e / sm;
        unsigned idx = (unsigned)n * 64u + lane;
        Sb[idx] = f2bf(sv);
        S8[idx] = f2fp8(sv * 64.f);
        dacc += (float)(s1 - s0) * sv * sv;
    }
    dacc = wave_sum(dacc);
    __shared__ float red[4];
    if (lane == 0) red[wib] = dacc;
    __syncthreads();
    if (threadIdx.x == 0) dtp[blockIdx.x] = red[0] + red[1] + red[2] + red[3];
}

// ---------------- pass 2: cut (fp8 gathers) ----------------
__global__ void cut_csr(const int* __restrict__ offsets, const int* __restrict__ csr_row,
                        const unsigned short* __restrict__ Sb,
                        const unsigned char* __restrict__ S8, float* __restrict__ cutp) {
    int lane = threadIdx.x & 63;
    int wib = threadIdx.x >> 6;
    int gw = (blockIdx.x * blockDim.x + threadIdx.x) >> 6;
    int nw = (gridDim.x * blockDim.x) >> 6;
    float acc = 0.f;
    for (int n = gw; n < N_NODES; n += nw) {
        float sc = bf2f(Sb[(unsigned)n * 64u + lane]);
        int s0 = offsets[n], s1 = offsets[n + 1];
        float g = 0.f;
        for (int base = s0; base < s1; base += 64) {
            int cnt = min(64, s1 - base);
            int rv = (lane < cnt) ? csr_row[base + lane] : 0;
            int j = 0;
            for (; j + 7 < cnt; j += 8) {
                unsigned o0 = (unsigned)__shfl(rv, j, 64) * 64u + lane;
                unsigned o1 = (unsigned)__shfl(rv, j + 1, 64) * 64u + lane;
                unsigned o2 = (unsigned)__shfl(rv, j + 2, 64) * 64u + lane;
                unsigned o3 = (unsigned)__shfl(rv, j + 3, 64) * 64u + lane;
                unsigned o4 = (unsigned)__shfl(rv, j + 4, 64) * 64u + lane;
                unsigned o5 = (unsigned)__shfl(rv, j + 5, 64) * 64u + lane;
                unsigned o6 = (unsigned)__shfl(rv, j + 6, 64) * 64u + lane;
                unsigned o7 = (unsigned)__shfl(rv, j + 7, 64) * 64u + lane;
                int b0 = S8[o0], b1 = S8[o1], b2 = S8[o2], b3 = S8[o3];
                int b4 = S8[o4], b5 = S8[o5], b6 = S8[o6], b7 = S8[o7];
                g += ((fp8tof(b0) + fp8tof(b1)) + (fp8tof(b2) + fp8tof(b3)))
                   + ((fp8tof(b4) + fp8tof(b5)) + (fp8tof(b6) + fp8tof(b7)));
            }
            for (; j < cnt; ++j) {
                unsigned o = (unsigned)__shfl(rv, j, 64) * 64u + lane;
                g += fp8tof(S8[o]);
            }
        }
        acc += sc * g * 0.015625f;     // undo x64 scale
    }
    acc = wave_sum(acc);
    __shared__ float red[4];
    if (lane == 0) red[wib] = acc;
    __syncthreads();
    if (threadIdx.x == 0) cutp[blockIdx.x] = red[0] + red[1] + red[2] + red[3];
}

// ---------------- SS = S^T S via MFMA, per-block partials ----------------
__global__ __launch_bounds__(256) void ss_mfma(const unsigned short* __restrict__ Sb,
                                               float* __restrict__ ssp) {
    __shared__ unsigned short Sr[32][66];
    int t = threadIdx.x;
    int lane = t & 63;
    int w = t >> 6;
    int m = lane & 15;
    int quad = lane >> 4;
    int srow = t >> 3;
    int spart = t & 7;

    f32x4 a0 = {0.f,0.f,0.f,0.f}, a1 = {0.f,0.f,0.f,0.f};
    f32x4 a2 = {0.f,0.f,0.f,0.f}, a3 = {0.f,0.f,0.f,0.f};

    for (int base = blockIdx.x * 32; base < N_NODES; base += SSP_BLOCKS * 32) {
        const uint4* g = (const uint4*)(Sb + (long long)(base + srow) * 64 + spart * 8);
        uint4 d = *g;
        __syncthreads();
        unsigned int* rowp = (unsigned int*)&Sr[srow][0];
        rowp[spart * 4 + 0] = d.x;
        rowp[spart * 4 + 1] = d.y;
        rowp[spart * 4 + 2] = d.z;
        rowp[spart * 4 + 3] = d.w;
        __syncthreads();

        short8 f0, f1, f2, f3;
#pragma unroll
        for (int j = 0; j < 8; ++j) {
            int k = quad * 8 + j;
            f0[j] = (short)Sr[k][m];
            f1[j] = (short)Sr[k][16 + m];
            f2[j] = (short)Sr[k][32 + m];
            f3[j] = (short)Sr[k][48 + m];
        }
        short8 fa = (w == 0) ? f0 : (w == 1) ? f1 : (w == 2) ? f2 : f3;
        a0 = __builtin_amdgcn_mfma_f32_16x16x32_bf16(fa, f0, a0, 0, 0, 0);
        a1 = __builtin_amdgcn_mfma_f32_16x16x32_bf16(fa, f1, a1, 0, 0, 0);
        a2 = __builtin_amdgcn_mfma_f32_16x16x32_bf16(fa, f2, a2, 0, 0, 0);
        a3 = __builtin_amdgcn_mfma_f32_16x16x32_bf16(fa, f3, a3, 0, 0, 0);
    }

    float* dst = ssp + (size_t)blockIdx.x * 4096;
#pragma unroll
    for (int r = 0; r < 4; ++r) {
        int row = w * 16 + quad * 4 + r;
        dst[row * 64 +  0 + m] = a0[r];
        dst[row * 64 + 16 + m] = a1[r];
        dst[row * 64 + 32 + m] = a2[r];
        dst[row * 64 + 48 + m] = a3[r];
    }
}

__global__ void reduce_ss(const float* __restrict__ ssp, float* __restrict__ SS) {
    int e = blockIdx.x * blockDim.x + threadIdx.x;
    float s = 0.f;
    for (int p = 0; p < SSP_BLOCKS; ++p) s += ssp[(size_t)p * 4096 + e];
    SS[e] = s;
}

// ---------------- scalar losses ----------------
__global__ void scalars_kernel(const float* __restrict__ cutp, const float* __restrict__ dtp,
                               const float* __restrict__ SS, float* __restrict__ out) {
    __shared__ float red[256];
    int t = threadIdx.x;
    float c = 0.f;
    for (int i = t; i < CUT_BLOCKS; i += 256) c += cutp[i];
    red[t] = c; __syncthreads();
    for (int s = 128; s; s >>= 1) { if (t < s) red[t] += red[t + s]; __syncthreads(); }
    float cut = red[0]; __syncthreads();

    float d = 0.f;
    for (int i = t; i < GATHER_BLOCKS; i += 256) d += dtp[i];
    red[t] = d; __syncthreads();
    for (int s = 128; s; s >>= 1) { if (t < s) red[t] += red[t + s]; __syncthreads(); }
    float dterm = red[0]; __syncthreads();

    float ss[16];
    float sq = 0.f;
#pragma unroll
    for (int j = 0; j < 16; ++j) { ss[j] = SS[t * 16 + j]; sq += ss[j] * ss[j]; }
    red[t] = sq; __syncthreads();
    for (int s = 128; s; s >>= 1) { if (t < s) red[t] += red[t + s]; __syncthreads(); }
    float nrm = sqrtf(red[0]); __syncthreads();

    float osq = 0.f;
#pragma unroll
    for (int j = 0; j < 16; ++j) {
        int idx = t * 16 + j;
        float v = ss[j] / nrm - ((idx % 65 == 0) ? 0.125f : 0.f);
        osq += v * v;
    }
    red[t] = osq; __syncthreads();
    for (int s = 128; s; s >>= 1) { if (t < s) red[t] += red[t + s]; __syncthreads(); }
    if (t == 0) {
        float loss = -(cut / dterm) + sqrtf(red[0]);
        out[(long long)N_NODES * OUT_C] = loss;
    }
}

// ---------------- output: barrier-free, one thread per row ----------------
__global__ __launch_bounds__(256) void out_kernel(const float* __restrict__ x,
                           const unsigned short* __restrict__ Sb,
                           const float* __restrict__ Weff, const float* __restrict__ beff,
                           float* __restrict__ out) {
    __shared__ float4 Wsh[192 * 4];
    __shared__ float bsh[16];
    int t = threadIdx.x;
    const float4* W4 = (const float4*)Weff;
    for (int i = t; i < 768; i += 256) Wsh[i] = W4[i];
    if (t < 16) bsh[t] = beff[t];
    __syncthreads();

    int r = blockIdx.x * 256 + t;
    if (r >= N_NODES) return;

    float4 p0 = make_float4(bsh[0], bsh[1], bsh[2], bsh[3]);
    float4 p1 = make_float4(bsh[4], bsh[5], bsh[6], bsh[7]);
    float4 p2 = make_float4(bsh[8], bsh[9], bsh[10], bsh[11]);
    float4 p3 = make_float4(bsh[12], bsh[13], bsh[14], bsh[15]);

    const float4* xr = (const float4*)(x + (long long)r * IN_C);
#pragma unroll 8
    for (int j = 0; j < 32; ++j) {
        float4 xv = xr[j];
        int k = j * 4;
        float xs[4] = {xv.x, xv.y, xv.z, xv.w};
#pragma unroll
        for (int c = 0; c < 4; ++c) {
            float s = xs[c];
            float4 w0 = Wsh[(k + c) * 4 + 0];
            float4 w1 = Wsh[(k + c) * 4 + 1];
            float4 w2 = Wsh[(k + c) * 4 + 2];
            float4 w3 = Wsh[(k + c) * 4 + 3];
            FMA4(p0, s, w0); FMA4(p1, s, w1); FMA4(p2, s, w2); FMA4(p3, s, w3);
        }
    }
    const uint2* sr = (const uint2*)(Sb + (long long)r * 64);
#pragma unroll 8
    for (int j = 0; j < 16; ++j) {
        uint2 u = sr[j];
        float xs[4] = {bf2f(u.x), bf2f(u.x >> 16), bf2f(u.y), bf2f(u.y >> 16)};
        int k = IN_C + j * 4;
#pragma unroll
        for (int c = 0; c < 4; ++c) {
            float s = xs[c];
            float4 w0 = Wsh[(k + c) * 4 + 0];
            float4 w1 = Wsh[(k + c) * 4 + 1];
            float4 w2 = Wsh[(k + c) * 4 + 2];
            float4 w3 = Wsh[(k + c) * 4 + 3];
            FMA4(p0, s, w0); FMA4(p1, s, w1); FMA4(p2, s, w2); FMA4(p3, s, w3);
        }
    }

    float m = fmaxf(fmaxf(fmaxf(p0.x, p0.y), fmaxf(p0.z, p0.w)),
                    fmaxf(fmaxf(fmaxf(p1.x, p1.y), fmaxf(p1.z, p1.w)),
                          fmaxf(fmaxf(fmaxf(p2.x, p2.y), fmaxf(p2.z, p2.w)),
                                fmaxf(fmaxf(p3.x, p3.y), fmaxf(p3.z, p3.w)))));
    float sum = __expf(p0.x - m) + __expf(p0.y - m) + __expf(p0.z - m) + __expf(p0.w - m)
              + __expf(p1.x - m) + __expf(p1.y - m) + __expf(p1.z - m) + __expf(p1.w - m)
              + __expf(p2.x - m) + __expf(p2.y - m) + __expf(p2.z - m) + __expf(p2.w - m)
              + __expf(p3.x - m) + __expf(p3.y - m) + __expf(p3.z - m) + __expf(p3.w - m);
    float lse = m + logf(sum);
    float4* o4 = (float4*)(out + (long long)r * OUT_C);
    o4[0] = make_float4(p0.x - lse, p0.y - lse, p0.z - lse, p0.w - lse);
    o4[1] = make_float4(p1.x - lse, p1.y - lse, p1.z - lse, p1.w - lse);
    o4[2] = make_float4(p2.x - lse, p2.y - lse, p2.z - lse, p2.w - lse);
    o4[3] = make_float4(p3.x - lse, p3.y - lse, p3.z - lse, p3.w - lse);
}

extern "C" void kernel_launch(void* const* d_in, const int* in_sizes, int n_in,
                              void* d_out, int out_size, void* d_ws, size_t ws_size,
                              hipStream_t stream) {
    const float* x     = (const float*)d_in[0];
    const int*   ei    = (const int*)d_in[1];
    const float* MLPW  = (const float*)d_in[2];
    const float* MLPb  = (const float*)d_in[3];
    const float* mlpxW = (const float*)d_in[4];
    const float* mlpxb = (const float*)d_in[5];
    const float* finW  = (const float*)d_in[6];
    const float* finb  = (const float*)d_in[7];
    float* out = (float*)d_out;
    char* ws = (char*)d_ws;

    unsigned char*  WT8 = (unsigned char*)ws;                        // N*64 B
    unsigned short* Sb  = (unsigned short*)(ws + (size_t)N_NODES * 64);      // N*64*2 B
    unsigned char*  S8  = (unsigned char*)(ws + (size_t)N_NODES * 192);      // N*64 B
    float* ssp  = (float*)(ws + (size_t)N_NODES * 256);              // 512*4096 f
    float* SS   = ssp + (size_t)SSP_BLOCKS * 4096;                   // 4096
    float* Weff = SS + 4096;                                         // 3072
    float* beff = Weff + 192 * 16;                                   // 16
    float* cutp = beff + 16;                                         // CUT_BLOCKS
    float* dtp  = cutp + CUT_BLOCKS;                                 // GATHER_BLOCKS
    int* ebuf    = (int*)(dtp + GATHER_BLOCKS);                      // E
    int* csr_row = ebuf + N_EDGES;                                   // E
    int* offsets = csr_row + N_EDGES;                                // N+1
    int* bcnt    = offsets + N_NODES + 1;                            // NBUCKET+1
    int* bbase   = bcnt + NBUCKET + 1;                               // NBUCKET+1
    int* bcur    = bbase + NBUCKET + 1;                              // NBUCKET

    hipLaunchKernelGGL(prep_weff, dim3(14), dim3(256), 0, stream,
                       mlpxW, mlpxb, finW, finb, Weff, beff, bcnt);
    hipLaunchKernelGGL(transpose_w, dim3(TRANS_BLOCKS), dim3(256), 0, stream, MLPW, WT8);
    hipLaunchKernelGGL(bucket_hist, dim3(NTILE), dim3(256), 0, stream, ei, bcnt);
    hipLaunchKernelGGL(bucket_scan, dim3(1), dim3(512), 0, stream, bcnt, bbase, bcur);
    hipLaunchKernelGGL(bucket_scatter, dim3(NTILE), dim3(256), 0, stream, ei, bcur, ebuf);
    hipLaunchKernelGGL(csr_build, dim3(NBUCKET), dim3(256), 0, stream,
                       ebuf, bbase, offsets, csr_row);
    hipLaunchKernelGGL(gather_softmax, dim3(GATHER_BLOCKS), dim3(256), 0, stream,
                       offsets, csr_row, WT8, MLPb, Sb, S8, dtp);
    hipLaunchKernelGGL(cut_csr, dim3(CUT_BLOCKS), dim3(256), 0, stream,
                       offsets, csr_row, Sb, S8, cutp);
    hipLaunchKernelGGL(ss_mfma, dim3(SSP_BLOCKS), dim3(256), 0, stream, Sb, ssp);
    hipLaunchKernelGGL(reduce_ss, dim3(16), dim3(256), 0, stream, ssp, SS);
    hipLaunchKernelGGL(scalars_kernel, dim3(1), dim3(256), 0, stream, cutp, dtp, SS, out);
    hipLaunchKernelGGL(out_kernel, dim3(OUT_BLOCKS), dim3(256), 0, stream, x, Sb, Weff, beff, out);
}